// Round 11
// baseline (589.930 us; speedup 1.0000x reference)
//
#include <hip/hip_runtime.h>
#include <stdint.h>

// ---------------- problem constants ----------------
#define INP_N   1024
#define NE_N    6400
#define NI_N    1600
#define NCOL    8000          // output neurons (E cols then I cols)
#define TS_N    1000
#define PRB0_T  200
#define TSPLIT  16            // sim state handoff at t=16 (steps 0..9 + tail 10..15)
#define NCHUNK  12            // 2x512 input rows + 10x800 recurrent rows
#define CAPTOT  992           // 2*56 + 10*88
#define IN_ENT  112           // input-region ELL entries per col (chunks 0,1)
#define BC      64            // k_build cols per block
#define CAPQ    36            // per-quarter staging cap (R9/R10-certified on device)
#define NBLD    (125 * 12)    // k_build block count

// ---------------- workspace layout ----------------
enum : size_t {
  ROWS_OFF = 0,                                          // u16[CAPTOT*NCOL]
  VALS_OFF = ROWS_OFF + (size_t)CAPTOT * NCOL * 2,       // f32[CAPTOT*NCOL]
  CNT_OFF  = VALS_OFF + (size_t)CAPTOT * NCOL * 4,       // i32[NCHUNK*NCOL]
  CSUM_OFF = CNT_OFF  + (size_t)NCHUNK * NCOL * 4,       // f32[NCHUNK*NCOL]
  DRV_OFF  = CSUM_OFF + (size_t)NCHUNK * NCOL * 4,       // f32[TS*NCOL]
  SE_OFF   = DRV_OFF  + (size_t)TS_N * NCOL * 4,         // f32[NCOL]
  SI_OFF   = SE_OFF   + (size_t)NCOL * 4,                // f32[NCOL]
  FLG_OFF  = SI_OFF   + (size_t)NCOL * 4,                // i32[TS]
  STV_OFF  = FLG_OFF  + (size_t)TS_N * 4,                // f32[8192]  v state
  STR_OFF  = STV_OFF  + (size_t)8192 * 4,                // u64[4*128] mask ring
  STT_OFF  = STR_OFF  + (size_t)512 * 8,                 // i32[8]     pEtot[4],pItot[4]
  SAB_OFF  = STT_OFF  + (size_t)8 * 4,                   // i32  all-fire at t=13,14,15
  AFL_OFF  = SAB_OFF  + 4,                               // i32  allflag t>=16
  MNP_OFF  = AFL_OFF  + 4,                               // f32[32]  block mins of sE+sI
  MNW_OFF  = MNP_OFF  + 32 * 4,                          // f32[64]  block mins input w
  STG_OFF  = MNW_OFF  + 64 * 4,                          // i32  strong proof flag
  OVA_OFF  = STG_OFF  + 4,                               // i32[NBLD] per-block ovf flags
  CTR_OFF  = OVA_OFF  + (size_t)NBLD * 4,                // u32[2] proof ctr, tail barrier
};

__device__ __forceinline__ void chunk_info(int c, int& j0, int& len, int& cap, int& off) {
  if (c < 2) { j0 = c * 512;            len = 512; cap = 56; off = c * 56; }
  else       { j0 = 1024 + (c - 2) * 800; len = 800; cap = 88; off = 112 + (c - 2) * 88; }
}

// ---------------- dense -> ELL-CSC build (register scan) + fused state init -------
// grid dim3(125,12), 256 thr. Wave w owns row-quarter w; lane reads its own column
// (coalesced), 16-row register double-buffer, zero ds_read in the scan. Padding is
// written for INPUT chunks only (k_drive/k_proof read fixed IN_ENT); recurrent
// chunks write kk < ktot only (consumers use cnt). Block (0,0) inits sim state.
__global__ void __launch_bounds__(256) k_build(
    const float* __restrict__ w_ae, const float* __restrict__ w_ai,
    uint16_t* __restrict__ rows, float* __restrict__ vals,
    int* __restrict__ cnt, float* __restrict__ csum, int* __restrict__ ovfA,
    float* __restrict__ gv, unsigned long long* __restrict__ gring,
    int* __restrict__ gtot, unsigned int* __restrict__ ctr) {
  __shared__ uint16_t rs_s[4 * CAPQ * BC];             // 18 KB
  __shared__ float    vs_s[4 * CAPQ * BC];             // 36 KB
  __shared__ int      kqs[4][BC];
  __shared__ float    sqs[4][BC];
  __shared__ int      wovf[4];
  const int tid   = threadIdx.x;
  const int lane  = tid & 63;
  const int wv    = tid >> 6;          // quarter index 0..3
  const int chunk = blockIdx.y;
  const int col0  = blockIdx.x * BC;

  if (blockIdx.x == 0 && blockIdx.y == 0) {   // fused init (ws 0xAA-poisoned)
    for (int i = tid; i < 8192; i += 256) gv[i] = 0.f;
    for (int i = tid; i < 512; i += 256)  gring[i] = 0ull;
    if (tid < 8) gtot[tid] = 0;
    if (tid < 2) ctr[tid] = 0u;
  }

  int j0, len, cap, off;
  chunk_info(chunk, j0, len, cap, off);
  const float* W; int nc, cc0;
  if (col0 < NE_N) { W = w_ae; nc = NE_N; cc0 = col0; }
  else             { W = w_ai; nc = NI_N; cc0 = col0 - NE_N; }

  const int qlen = len >> 2;           // 128 (input) or 200 (recurrent)
  const int j0w  = j0 + wv * qlen;
  const float* Wc = W + (size_t)j0w * nc + cc0 + lane;   // this lane's column base

  float cur[16], nxt[16];
  #pragma unroll
  for (int r = 0; r < 16; ++r) cur[r] = Wc[(size_t)r * nc];

  int k = 0; float s = 0.f; int ovfl = 0;
  for (int t0 = 0; t0 < qlen; t0 += 16) {
    const int nt = t0 + 16;
    if (nt < qlen) {                   // prefetch next batch (independent loads)
      #pragma unroll
      for (int r = 0; r < 16; ++r) {
        int rq = nt + r; rq = rq < qlen ? rq : qlen - 1;
        nxt[r] = Wc[(size_t)rq * nc];
      }
    }
    const int rlim = (qlen - t0) < 16 ? (qlen - t0) : 16;
    #pragma unroll
    for (int r = 0; r < 16; ++r) {
      if (r < rlim) {
        float w = cur[r];
        if (w != 0.f) {
          if (k < CAPQ) {
            rs_s[(wv * CAPQ + k) * BC + lane] = (uint16_t)(j0w + t0 + r);
            vs_s[(wv * CAPQ + k) * BC + lane] = w;
            s += w; ++k;               // ascending-row order == reference scan
          } else ovfl = 1;             // dropped nonzero -> void strong proof
        }
      }
    }
    #pragma unroll
    for (int r = 0; r < 16; ++r) cur[r] = nxt[r];
  }
  kqs[wv][lane] = k;
  sqs[wv][lane] = s;
  if (lane == 0) wovf[wv] = 0;
  int anyo = __any(ovfl);
  if (lane == 0) wovf[wv] = anyo;
  __syncthreads();

  // merge + coalesced writeback: thread t -> col=t&63, levels kk = t>>6 + 4j
  const int col = lane;
  const int k0 = kqs[0][col], k1 = kqs[1][col], k2 = kqs[2][col], k3 = kqs[3][col];
  const int c1 = k0, c2 = k0 + k1, c3 = c2 + k2, ktot = c3 + k3;
  if (tid < BC) {
    cnt[chunk * NCOL + col0 + col]  = ktot < cap ? ktot : cap;
    csum[chunk * NCOL + col0 + col] = ((sqs[0][col] + sqs[1][col]) + sqs[2][col]) + sqs[3][col];
    unsigned long long capov = __ballot(ktot > cap);
    if (tid == 0)
      ovfA[blockIdx.y * gridDim.x + blockIdx.x] =
        (capov ? 1 : 0) | wovf[0] | wovf[1] | wovf[2] | wovf[3];
  }
  const int wlim = (chunk < 2) ? cap : (ktot < cap ? ktot : cap);   // pad input only
  const size_t gb = (size_t)off * NCOL + col0;
  for (int kk = wv; kk < wlim; kk += 4) {
    uint16_t rr = (uint16_t)j0; float vv = 0.f;
    if (kk < ktot) {
      int q, loc;
      if      (kk < c1) { q = 0; loc = kk; }
      else if (kk < c2) { q = 1; loc = kk - c1; }
      else if (kk < c3) { q = 2; loc = kk - c2; }
      else              { q = 3; loc = kk - c3; }
      rr = rs_s[(q * CAPQ + loc) * BC + col];   // addr%32 == col%32 -> conflict-free
      vv = vs_s[(q * CAPQ + loc) * BC + col];
    }
    rows[gb + (size_t)kk * NCOL + col] = rr;    // 64 contiguous cols: full lines
    vals[gb + (size_t)kk * NCOL + col] = vv;
  }
}

// ---------------- fused proof: partial reductions + last-block strong verdict -----
__global__ void __launch_bounds__(256) k_proof(
    const float* __restrict__ csum, float* __restrict__ sE, float* __restrict__ sI,
    const float* __restrict__ vals, float* __restrict__ minpart, float* __restrict__ mwpart,
    const int* __restrict__ ovfA, unsigned int* __restrict__ ctr, int* __restrict__ strongp) {
  const int tid = threadIdx.x;
  const int b = blockIdx.x;     // 96 blocks
  __shared__ float w4[4];
  __shared__ int lastS;
  float m = 1e30f;
  if (b < 32) {                       // per-col saturated sums + min of fl(sE+sI)
    int col = b * 256 + tid;
    if (col < NCOL) {
      float se = 0.f;
      #pragma unroll
      for (int c = 2; c <= 9; ++c) se += csum[c * NCOL + col];
      float si = csum[10 * NCOL + col] + csum[11 * NCOL + col];
      sE[col] = se;
      sI[col] = si;
      m = se + si;   // fp-add monotone: (drive+se)+si >= fl(se+si) when drive>=0
    }
  } else {                            // min over input-chunk ELL vals (drive >= 0 cert)
    const int n = IN_ENT * NCOL;
    for (int i = (b - 32) * 256 + tid; i < n; i += 64 * 256)
      m = fminf(m, vals[i]);
  }
  #pragma unroll
  for (int o = 32; o; o >>= 1) m = fminf(m, __shfl_down(m, o));
  if ((tid & 63) == 0) w4[tid >> 6] = m;
  __syncthreads();
  if (tid == 0) {
    float r = fminf(fminf(w4[0], w4[1]), fminf(w4[2], w4[3]));
    if (b < 32) minpart[b] = r; else mwpart[b - 32] = r;
    __threadfence();
    unsigned p = __hip_atomic_fetch_add(&ctr[0], 1u, __ATOMIC_ACQ_REL, __HIP_MEMORY_SCOPE_AGENT);
    lastS = (p == 95) ? 1 : 0;
  }
  __syncthreads();
  if (!lastS) return;
  __threadfence();                    // acquire: all 96 partials now visible
  float mb = (tid < 32) ? __hip_atomic_load(&minpart[tid], __ATOMIC_RELAXED, __HIP_MEMORY_SCOPE_AGENT) : 1e30f;
  float mw = (tid < 64) ? __hip_atomic_load(&mwpart[tid],  __ATOMIC_RELAXED, __HIP_MEMORY_SCOPE_AGENT) : 1e30f;
  int ov = 0;
  for (int i = tid; i < NBLD; i += 256)
    ov |= __hip_atomic_load(&ovfA[i], __ATOMIC_RELAXED, __HIP_MEMORY_SCOPE_AGENT);
  #pragma unroll
  for (int o = 32; o; o >>= 1) {
    mb = fminf(mb, __shfl_down(mb, o));
    mw = fminf(mw, __shfl_down(mw, o));
    ov |= __shfl_down(ov, o);
  }
  __shared__ float fm[4], fw[4]; __shared__ int fo[4];
  if ((tid & 63) == 0) { fm[tid >> 6] = mb; fw[tid >> 6] = mw; fo[tid >> 6] = ov; }
  __syncthreads();
  if (tid == 0) {
    float MB = fminf(fminf(fm[0], fm[1]), fminf(fm[2], fm[3]));
    float MW = fminf(fminf(fw[0], fw[1]), fminf(fw[2], fw[3]));
    int   OV = fo[0] | fo[1] | fo[2] | fo[3];
    strongp[0] = (MB >= 1.0f && MW >= 0.0f && OV == 0) ? 1 : 0;
  }
}

// ---------------- input drive (spikes computed inline from rand_p) ----------------
// pass 0 (strong): y<4 -> t in [4y,4y+4); y>=4 exit.  (!strong): y -> [40y,40y+40).
// pass 1 (strong && !sab only): y==0 -> [16,40); y>0 -> [40y,40y+40).
__global__ void __launch_bounds__(256) k_drive(
    const uint16_t* __restrict__ rows, const float* __restrict__ vals,
    const float* __restrict__ rand_p, const float* __restrict__ inp,
    float* __restrict__ drive,
    const int* __restrict__ strongp, const int* __restrict__ sabp, int pass) {
  int t0, t1;
  if (pass == 0) {
    if (strongp[0]) {
      if (blockIdx.y >= 4) return;
      t0 = blockIdx.y * 4; t1 = t0 + 4;
    } else { t0 = blockIdx.y * 40; t1 = t0 + 40; }
  } else {
    if (!strongp[0] || sabp[0]) return;
    t0 = blockIdx.y * 40; t1 = t0 + 40;
    if (blockIdx.y == 0) t0 = TSPLIT;   // backfill what pass 0 skipped
  }
  __shared__ uint16_t rs[IN_ENT * 64];
  __shared__ float    vs[IN_ENT * 64];
  __shared__ float    inps[INP_N];
  __shared__ float    act0[INP_N];
  __shared__ float    psum[4][64];
  const int tid = threadIdx.x, lane = tid & 63, ph = tid >> 6;
  const int col0 = blockIdx.x * 64;
  for (int idx = tid; idx < IN_ENT * 64; idx += 256) {   // stage ELL once (coalesced)
    int k = idx >> 6, l = idx & 63;
    rs[idx] = rows[(size_t)k * NCOL + col0 + l];
    vs[idx] = vals[(size_t)k * NCOL + col0 + l];
  }
  for (int i = tid; i < INP_N; i += 256) inps[i] = inp[i] * 0.5f;  // rate_scale
  __syncthreads();
  for (int t = t0; t < t1; ++t) {
    #pragma unroll
    for (int i = tid; i < INP_N; i += 256)
      act0[i] = (rand_p[(size_t)t * INP_N + i] <= inps[i]) ? 1.f : 0.f;
    __syncthreads();
    float acc = 0.f;
    for (int k = ph; k < IN_ENT; k += 4)
      acc += vs[k * 64 + lane] * act0[rs[k * 64 + lane]];
    psum[ph][lane] = acc;
    __syncthreads();
    if (ph == 0)
      drive[(size_t)t * NCOL + col0 + lane] =
        ((psum[0][lane] + psum[1][lane]) + psum[2][lane]) + psum[3][lane];
    __syncthreads();
  }
}

// ---------------- one grid-wide transient step (t=0..9) ----------------
__global__ void __launch_bounds__(512) k_step(
    const uint16_t* __restrict__ rows, const float* __restrict__ vals,
    const int* __restrict__ cnt, const float* __restrict__ sE,
    const float* __restrict__ sI, const float* __restrict__ drive,
    float* __restrict__ gv, unsigned long long* __restrict__ gring,
    int* __restrict__ gtot, const int* __restrict__ strongp, int t) {
  __shared__ unsigned long long m[128];
  __shared__ float psum[8][64];
  const int tid = threadIdx.x, lane = tid & 63, ph = tid >> 6;
  const int blk = blockIdx.x;
  const bool isE = (blk < 100);
  const int sw = t & 3, s1 = (t + 3) & 3, s2 = (t + 2) & 3;

  // ultra-fast: strong + 2 consecutive all-fire steps => provably all-fire again
  const bool full1 = (gtot[s1] == NE_N) && (gtot[4 + s1] == NI_N);
  const bool full2 = (gtot[s2] == NE_N) && (gtot[4 + s2] == NI_N);
  if (strongp[0] && full1 && full2) {
    if (tid == 0) {
      gring[sw * 128 + blk] = ~0ull;
      if (blk == 0) { gtot[sw] = NE_N; gtot[4 + sw] = NI_N; }
    }
    return;
  }

  const int sEs = isE ? s2 : s1;   // E targets: E rows t-2, I rows t-1; I reversed
  const int sIs = isE ? s1 : s2;
  const int col = blk * 64 + lane;

  if (tid < 100)      m[tid] = gring[sEs * 128 + tid];
  else if (tid < 125) m[tid] = gring[sIs * 128 + tid];
  const int pEv = gtot[sEs];
  const int pIv = gtot[4 + sIs];
  if (blk == 0 && tid == 0) { gtot[(t + 1) & 3] = 0; gtot[4 + ((t + 1) & 3)] = 0; }
  __syncthreads();

  float acc = 0.f;
  if (pEv > 0 && pEv < NE_N) {
    for (int c = 2; c <= 9; ++c) {
      int cn = cnt[c * NCOL + col];
      size_t base = (size_t)(112 + (c - 2) * 88) * NCOL + col;
      for (int k = ph; k < cn; k += 8) {
        int r = rows[base + (size_t)k * NCOL] - 1024;
        float wv = vals[base + (size_t)k * NCOL];
        if ((m[r >> 6] >> (r & 63)) & 1ull) acc += wv;
      }
    }
  }
  if (pIv > 0 && pIv < NI_N) {
    for (int c = 10; c <= 11; ++c) {
      int cn = cnt[c * NCOL + col];
      size_t base = (size_t)(112 + (c - 2) * 88) * NCOL + col;
      for (int k = ph; k < cn; k += 8) {
        int r = rows[base + (size_t)k * NCOL] - 1024;
        float wv = vals[base + (size_t)k * NCOL];
        if ((m[r >> 6] >> (r & 63)) & 1ull) acc += wv;
      }
    }
  }
  psum[ph][lane] = acc;
  __syncthreads();

  if (ph == 0) {
    float tot = drive[(size_t)t * NCOL + col]
              + ((psum[0][lane] + psum[1][lane]) + (psum[2][lane] + psum[3][lane]))
              + ((psum[4][lane] + psum[5][lane]) + (psum[6][lane] + psum[7][lane]));
    if (pEv == NE_N) tot += sE[col];
    if (pIv == NI_N) tot += sI[col];
    float vn = gv[col] * 0.95f + tot;
    int s = (vn >= 0.5f) ? 1 : 0;
    gv[col] = s ? 0.f : vn;
    unsigned long long bal = __ballot(s);
    int pc = __popcll(bal);
    if (lane == 0) {
      gring[sw * 128 + blk] = bal;
      if (isE) atomicAdd(&gtot[sw], pc);
      else     atomicAdd(&gtot[4 + sw], pc);
    }
  }
}

// ---------------- k_tail: steps t=10..15 in ONE launch -----------------------------
// Likely path: strong + all-fire at t=8 (slot0) and t=9 (slot1) => by induction all
// of t=10..15 are all-fire; block 0 writes all 4 ring slots/totals full; done.
// Dormant path: real steps with an R1-style device-wide barrier (agent atomics).
__global__ void __launch_bounds__(512) k_tail(
    const uint16_t* __restrict__ rows, const float* __restrict__ vals,
    const int* __restrict__ cnt, const float* __restrict__ sE,
    const float* __restrict__ sI, const float* __restrict__ drive,
    float* __restrict__ gv, unsigned long long* __restrict__ gring,
    int* __restrict__ gtot, const int* __restrict__ strongp,
    unsigned int* __restrict__ ctr) {
  __shared__ unsigned long long m[128];
  __shared__ float psum[8][64];
  const int tid = threadIdx.x, lane = tid & 63, ph = tid >> 6;
  const int blk = blockIdx.x;
  const bool isE = (blk < 100);

  const bool full8 = (gtot[0] == NE_N) && (gtot[4] == NI_N);   // t=8 -> slot 0
  const bool full9 = (gtot[1] == NE_N) && (gtot[5] == NI_N);   // t=9 -> slot 1
  if (strongp[0] && full8 && full9) {
    if (blk == 0) {
      for (int i = tid; i < 512; i += 512) gring[i] = ~0ull;
      if (tid < 4) { gtot[tid] = NE_N; gtot[4 + tid] = NI_N; }
    }
    return;
  }

  // ---- dormant: exact steps 10..15, device barrier between steps ----
  for (int t = 10; t < 16; ++t) {
    const int sw = t & 3, s1 = (t + 3) & 3, s2 = (t + 2) & 3;
    const int sEs = isE ? s2 : s1, sIs = isE ? s1 : s2;
    if (tid < 100)
      m[tid] = __hip_atomic_load(&gring[sEs * 128 + tid], __ATOMIC_RELAXED, __HIP_MEMORY_SCOPE_AGENT);
    else if (tid < 125)
      m[tid] = __hip_atomic_load(&gring[sIs * 128 + tid], __ATOMIC_RELAXED, __HIP_MEMORY_SCOPE_AGENT);
    const int pEv = __hip_atomic_load(&gtot[sEs], __ATOMIC_RELAXED, __HIP_MEMORY_SCOPE_AGENT);
    const int pIv = __hip_atomic_load(&gtot[4 + sIs], __ATOMIC_RELAXED, __HIP_MEMORY_SCOPE_AGENT);
    if (blk == 0 && tid == 0) {
      __hip_atomic_store(&gtot[(t + 1) & 3], 0, __ATOMIC_RELAXED, __HIP_MEMORY_SCOPE_AGENT);
      __hip_atomic_store(&gtot[4 + ((t + 1) & 3)], 0, __ATOMIC_RELAXED, __HIP_MEMORY_SCOPE_AGENT);
    }
    __syncthreads();

    const int col = blk * 64 + lane;
    float acc = 0.f;
    if (pEv > 0 && pEv < NE_N) {
      for (int c = 2; c <= 9; ++c) {
        int cn = cnt[c * NCOL + col];
        size_t base = (size_t)(112 + (c - 2) * 88) * NCOL + col;
        for (int k = ph; k < cn; k += 8) {
          int r = rows[base + (size_t)k * NCOL] - 1024;
          float wv = vals[base + (size_t)k * NCOL];
          if ((m[r >> 6] >> (r & 63)) & 1ull) acc += wv;
        }
      }
    }
    if (pIv > 0 && pIv < NI_N) {
      for (int c = 10; c <= 11; ++c) {
        int cn = cnt[c * NCOL + col];
        size_t base = (size_t)(112 + (c - 2) * 88) * NCOL + col;
        for (int k = ph; k < cn; k += 8) {
          int r = rows[base + (size_t)k * NCOL] - 1024;
          float wv = vals[base + (size_t)k * NCOL];
          if ((m[r >> 6] >> (r & 63)) & 1ull) acc += wv;
        }
      }
    }
    psum[ph][lane] = acc;
    __syncthreads();

    if (ph == 0) {
      float tot = drive[(size_t)t * NCOL + col]
                + ((psum[0][lane] + psum[1][lane]) + (psum[2][lane] + psum[3][lane]))
                + ((psum[4][lane] + psum[5][lane]) + (psum[6][lane] + psum[7][lane]));
      if (pEv == NE_N) tot += sE[col];
      if (pIv == NI_N) tot += sI[col];
      float vn = gv[col] * 0.95f + tot;
      int s = (vn >= 0.5f) ? 1 : 0;
      gv[col] = s ? 0.f : vn;
      unsigned long long bal = __ballot(s);
      int pc = __popcll(bal);
      if (lane == 0) {
        __hip_atomic_store(&gring[sw * 128 + blk], bal, __ATOMIC_RELAXED, __HIP_MEMORY_SCOPE_AGENT);
        if (isE) atomicAdd(&gtot[sw], pc);
        else     atomicAdd(&gtot[4 + sw], pc);
      }
    }
    __syncthreads();
    if (tid == 0) {       // device barrier (monotonic, agent scope)
      __threadfence();
      __hip_atomic_fetch_add(&ctr[1], 1u, __ATOMIC_RELEASE, __HIP_MEMORY_SCOPE_AGENT);
      const unsigned tgt = (unsigned)(t - 9) * 125;
      while (__hip_atomic_load(&ctr[1], __ATOMIC_ACQUIRE, __HIP_MEMORY_SCOPE_AGENT) < tgt)
        __builtin_amdgcn_s_sleep(1);
    }
    __syncthreads();
  }
}

// ---------------- sab: all-fire at t=13 (slot1), t=14 (slot2), t=15 (slot3) -------
__global__ void k_sab(const int* __restrict__ gtot, int* __restrict__ sab) {
  sab[0] = (gtot[1] == NE_N && gtot[2] == NE_N && gtot[3] == NE_N &&
            gtot[5] == NI_N && gtot[6] == NI_N && gtot[7] == NI_N) ? 1 : 0;
}

// ---------------- flag[t] (125 strided blocks; pure early-exit when proven) -------
__global__ void __launch_bounds__(256) k_check2(
    const float* __restrict__ drive, const float* __restrict__ sE,
    const float* __restrict__ sI, int* __restrict__ flag,
    const int* __restrict__ strongp, const int* __restrict__ sabp) {
  if (strongp[0] && sabp[0]) return;
  const int tid = threadIdx.x;
  __shared__ int w4[4];
  for (int t = blockIdx.x; t < TS_N; t += 125) {
    const float* dr = drive + (size_t)t * NCOL;
    int nb = 0;
    for (int col = tid; col < NCOL; col += 256) {
      float vn = (dr[col] + sE[col]) + sI[col];
      nb += (vn >= 0.5f) ? 0 : 1;
    }
    #pragma unroll
    for (int o = 32; o; o >>= 1) nb += __shfl_down(nb, o);
    if ((tid & 63) == 0) w4[tid >> 6] = nb;
    __syncthreads();
    if (tid == 0) flag[t] = ((w4[0] + w4[1]) + (w4[2] + w4[3])) == 0 ? 1 : 0;
    __syncthreads();
  }
}

// ---------------- allflag: strong proof OR AND of flag[t>=TSPLIT] ----------------
__global__ void k_fin(const int* __restrict__ flag, const int* __restrict__ strongp,
                      int* __restrict__ allflag) {
  const int tid = threadIdx.x;   // 256
  if (strongp[0]) { if (tid == 0) allflag[0] = 1; return; }
  int bad = 0;
  for (int i = TSPLIT + tid; i < TS_N; i += 256) bad += (flag[i] == 0) ? 1 : 0;
  #pragma unroll
  for (int o = 32; o; o >>= 1) bad += __shfl_down(bad, o);
  __shared__ int w4[4];
  if ((tid & 63) == 0) w4[tid >> 6] = bad;
  __syncthreads();
  if (tid == 0) allflag[0] = ((w4[0] + w4[1]) + (w4[2] + w4[3])) == 0 ? 1 : 0;
}

// ---------------- k_simB: t in [TSPLIT, TS); short-circuits if saturation proven ----
__global__ void __launch_bounds__(1024) k_simB(
    const uint16_t* __restrict__ rows, const float* __restrict__ vals,
    const int* __restrict__ cnt, const float* __restrict__ sE,
    const float* __restrict__ sI, const float* __restrict__ drive,
    const int* __restrict__ flag,
    const float* __restrict__ stv, const unsigned long long* __restrict__ str_,
    const int* __restrict__ stt, const int* __restrict__ sab,
    const int* __restrict__ allflag, float* __restrict__ out) {
  __shared__ unsigned long long ring[4][128];
  __shared__ int pEtot[4], pItot[4];
  __shared__ int flagsL[TS_N];
  __shared__ int fastexit;

  const int tid  = threadIdx.x;
  const int lane = tid & 63;
  const int wv   = tid >> 6;

  if (tid == 0) fastexit = (sab[0] != 0) && (allflag[0] != 0);
  __syncthreads();

  if (fastexit) {
    // all-fire at 13,14,15 + (strong proof or per-t flags) for t>=16 => v stays 0,
    // every col fires every step t>=16; probe [200,1000) => 800/800 = 1.0 exactly.
    #pragma unroll
    for (int p = 0; p < 8; ++p) {
      int col = p * 1024 + tid;
      if (col < NE_N) out[col] = 1.0f;
    }
    return;
  }

  // ---- verified fallback: 1-CU sequential loop from saved transient state ----
  for (int i = tid; i < 512; i += 1024) (&ring[0][0])[i] = str_[i];
  if (tid < 4) { pEtot[tid] = stt[tid]; pItot[tid] = stt[4 + tid]; }
  for (int i = tid; i < TS_N; i += 1024) flagsL[i] = flag[i];

  float v[8], sEr[8], sIr[8];
  int spk[8];
  #pragma unroll
  for (int p = 0; p < 8; ++p) {
    int col = p * 1024 + tid;
    sEr[p] = (col < NCOL) ? sE[col] : 0.f;
    sIr[p] = (col < NCOL) ? sI[col] : 0.f;
    v[p] = (col < NCOL) ? stv[col] : 0.f; spk[p] = 0;
  }
  int spkAll = 0, fastAge = 0;
  __syncthreads();

  for (int t = TSPLIT; t < TS_N; ++t) {
    const int sw = t & 3, s1 = (t + 3) & 3, s2 = (t + 2) & 3;
    int pE1, pI1, pE2, pI2;
    if (fastAge >= 2)      { pE1 = pE2 = NE_N; pI1 = pI2 = NI_N; }
    else if (fastAge == 1) { pE1 = NE_N; pI1 = NI_N; pE2 = pEtot[s2]; pI2 = pItot[s2]; }
    else                   { pE1 = pEtot[s1]; pI1 = pItot[s1]; pE2 = pEtot[s2]; pI2 = pItot[s2]; }
    const bool satE1 = (pE1 == NE_N), satE2 = (pE2 == NE_N);
    const bool satI1 = (pI1 == NI_N), satI2 = (pI2 == NI_N);

    if (satE1 && satI1 && satE2 && satI2 && flagsL[t]) {
      if (t >= PRB0_T) ++spkAll;
      ++fastAge;
      continue;
    }

    if (fastAge > 0) {
      for (int i = tid; i < 128; i += 1024) {
        ring[s1][i] = ~0ull;
        if (fastAge >= 2) ring[s2][i] = ~0ull;
      }
    }
    if (tid == 0) {
      if (fastAge > 0) {
        pEtot[s1] = NE_N; pItot[s1] = NI_N;
        if (fastAge >= 2) { pEtot[s2] = NE_N; pItot[s2] = NI_N; }
      }
      pEtot[sw] = 0; pItot[sw] = 0;
    }
    __syncthreads();
    fastAge = 0;

    const float* dr = drive + (size_t)t * NCOL;
    int myE = 0, myI = 0;
    #pragma unroll
    for (int p = 0; p < 8; ++p) {
      int col = p * 1024 + tid;
      bool isEcol = col < NE_N;
      int pEv = isEcol ? pE2 : pE1;
      int pIv = isEcol ? pI1 : pI2;
      int sEs = isEcol ? s2 : s1;
      int sIs = isEcol ? s1 : s2;
      float tot = (col < NCOL) ? dr[col] : 0.f;
      if (col < NCOL) {
        if (pEv == NE_N) tot += sEr[p];
        else if (pEv > 0) {
          for (int c = 2; c <= 9; ++c) {
            int cn = cnt[c * NCOL + col];
            size_t base = (size_t)(112 + (c - 2) * 88) * NCOL + col;
            for (int k = 0; k < cn; ++k) {
              int j = rows[base + (size_t)k * NCOL];
              float wval = vals[base + (size_t)k * NCOL];
              int r = j - 1024;
              if ((ring[sEs][r >> 6] >> (r & 63)) & 1ull) tot += wval;
            }
          }
        }
        if (pIv == NI_N) tot += sIr[p];
        else if (pIv > 0) {
          for (int c = 10; c <= 11; ++c) {
            int cn = cnt[c * NCOL + col];
            size_t base = (size_t)(112 + (c - 2) * 88) * NCOL + col;
            for (int k = 0; k < cn; ++k) {
              int j = rows[base + (size_t)k * NCOL];
              float wval = vals[base + (size_t)k * NCOL];
              int r = j - 1024;
              if ((ring[sIs][r >> 6] >> (r & 63)) & 1ull) tot += wval;
            }
          }
        }
      }
      float vn = v[p] * 0.95f + tot;
      int s = (col < NCOL) && (vn >= 0.5f);
      v[p] = s ? 0.f : vn;
      if (t >= PRB0_T && isEcol) spk[p] += s;
      unsigned long long bal = __ballot(s);
      int word = p * 16 + wv;
      if (word < 125) {
        int pc = __popcll(bal);
        if (word < 100) myE += pc; else myI += pc;
        if (lane == 0) ring[sw][word] = bal;
      }
    }
    if (lane == 0) { atomicAdd(&pEtot[sw], myE); atomicAdd(&pItot[sw], myI); }
    __syncthreads();
  }

  #pragma unroll
  for (int p = 0; p < 8; ++p) {
    int col = p * 1024 + tid;
    if (col < NE_N) out[col] = (float)(spk[p] + spkAll) / 800.0f;
  }
}

// ---------------- launch (18 dispatches) ----------------
extern "C" void kernel_launch(void* const* d_in, const int* in_sizes, int n_in,
                              void* d_out, int out_size, void* d_ws, size_t ws_size,
                              hipStream_t stream) {
  const float* inp    = (const float*)d_in[0];
  const float* w_ae   = (const float*)d_in[1];
  const float* w_ai   = (const float*)d_in[2];
  const float* rand_p = (const float*)d_in[3];

  char* ws = (char*)d_ws;
  uint16_t*           rows    = (uint16_t*)(ws + ROWS_OFF);
  float*              vals    = (float*)(ws + VALS_OFF);
  int*                cnt     = (int*)(ws + CNT_OFF);
  float*              csum    = (float*)(ws + CSUM_OFF);
  float*              drive   = (float*)(ws + DRV_OFF);
  float*              sEa     = (float*)(ws + SE_OFF);
  float*              sIa     = (float*)(ws + SI_OFF);
  int*                flag    = (int*)(ws + FLG_OFF);
  float*              gv      = (float*)(ws + STV_OFF);
  unsigned long long* gring   = (unsigned long long*)(ws + STR_OFF);
  int*                gtot    = (int*)(ws + STT_OFF);
  int*                sab     = (int*)(ws + SAB_OFF);
  int*                afl     = (int*)(ws + AFL_OFF);
  float*              minpart = (float*)(ws + MNP_OFF);
  float*              mwpart  = (float*)(ws + MNW_OFF);
  int*                strg    = (int*)(ws + STG_OFF);
  int*                ovfA    = (int*)(ws + OVA_OFF);
  unsigned int*       ctr     = (unsigned int*)(ws + CTR_OFF);

  k_build<<<dim3(NCOL / BC, NCHUNK), 256, 0, stream>>>(w_ae, w_ai, rows, vals, cnt, csum,
                                                       ovfA, gv, gring, gtot, ctr);
  k_proof<<<96, 256, 0, stream>>>(csum, sEa, sIa, vals, minpart, mwpart, ovfA, ctr, strg);
  k_drive<<<dim3(125, 25), 256, 0, stream>>>(rows, vals, rand_p, inp, drive, strg, sab, 0);
  for (int t = 0; t < 10; ++t)
    k_step<<<125, 512, 0, stream>>>(rows, vals, cnt, sEa, sIa, drive, gv, gring, gtot, strg, t);
  k_tail<<<125, 512, 0, stream>>>(rows, vals, cnt, sEa, sIa, drive, gv, gring, gtot, strg, ctr);
  k_sab<<<1, 1, 0, stream>>>(gtot, sab);
  // lazy fallback fill: only active if strong proof held but transient did not saturate
  k_drive<<<dim3(125, 25), 256, 0, stream>>>(rows, vals, rand_p, inp, drive, strg, sab, 1);
  k_check2<<<125, 256, 0, stream>>>(drive, sEa, sIa, flag, strg, sab);
  k_fin<<<1, 256, 0, stream>>>(flag, strg, afl);
  k_simB<<<1, 1024, 0, stream>>>(rows, vals, cnt, sEa, sIa, drive, flag,
                                 gv, gring, gtot, sab, afl, (float*)d_out);
}

// Round 12
// 534.014 us; speedup vs baseline: 1.1047x; 1.1047x over previous
//
#include <hip/hip_runtime.h>
#include <stdint.h>

// ---------------- problem constants ----------------
#define INP_N   1024
#define NE_N    6400
#define NI_N    1600
#define NCOL    8000          // output neurons (E cols then I cols)
#define TS_N    1000
#define PRB0_T  200
#define TSPLIT  16            // sim state handoff at t=16 (steps 0..9 + tail 10..15)
#define NCHUNK  12            // 2x512 input rows + 10x800 recurrent rows
#define CAPTOT  992           // 2*56 + 10*88
#define IN_ENT  112           // input-region ELL entries per col (chunks 0,1)
#define BC      64            // k_build cols per block
#define NWV     8             // k_build waves (row-eighths)
#define CAPE    24            // per-eighth staging cap (100-row eighth: ~9 sigma)
#define NBLD    (125 * 12)    // k_build block count

// ---------------- workspace layout ----------------
enum : size_t {
  ROWS_OFF = 0,                                          // u16[CAPTOT*NCOL]
  VALS_OFF = ROWS_OFF + (size_t)CAPTOT * NCOL * 2,       // f32[CAPTOT*NCOL]
  CNT_OFF  = VALS_OFF + (size_t)CAPTOT * NCOL * 4,       // i32[NCHUNK*NCOL]
  CSUM_OFF = CNT_OFF  + (size_t)NCHUNK * NCOL * 4,       // f32[NCHUNK*NCOL]
  DRV_OFF  = CSUM_OFF + (size_t)NCHUNK * NCOL * 4,       // f32[TS*NCOL]
  SE_OFF   = DRV_OFF  + (size_t)TS_N * NCOL * 4,         // f32[NCOL]
  SI_OFF   = SE_OFF   + (size_t)NCOL * 4,                // f32[NCOL]
  FLG_OFF  = SI_OFF   + (size_t)NCOL * 4,                // i32[TS]
  STV_OFF  = FLG_OFF  + (size_t)TS_N * 4,                // f32[8192]  v state
  STR_OFF  = STV_OFF  + (size_t)8192 * 4,                // u64[4*128] mask ring
  STT_OFF  = STR_OFF  + (size_t)512 * 8,                 // i32[8]     pEtot[4],pItot[4]
  SAB_OFF  = STT_OFF  + (size_t)8 * 4,                   // i32  all-fire at t=13,14,15
  AFL_OFF  = SAB_OFF  + 4,                               // i32  allflag t>=16
  MNP_OFF  = AFL_OFF  + 4,                               // f32[32]  block mins of sE+sI
  MNW_OFF  = MNP_OFF  + 32 * 4,                          // f32[64]  block mins input w
  STG_OFF  = MNW_OFF  + 64 * 4,                          // i32  strong proof flag
  OVA_OFF  = STG_OFF  + 4,                               // i32[NBLD] per-block ovf flags
  CTR_OFF  = OVA_OFF  + (size_t)NBLD * 4,                // u32[2] proof ctr, tail barrier
};

__device__ __forceinline__ void chunk_info(int c, int& j0, int& len, int& cap, int& off) {
  if (c < 2) { j0 = c * 512;            len = 512; cap = 56; off = c * 56; }
  else       { j0 = 1024 + (c - 2) * 800; len = 800; cap = 88; off = 112 + (c - 2) * 88; }
}

// ---------------- dense -> ELL-CSC build: 8 row-eighth waves, register scan -------
// grid dim3(125,12), 512 thr. Wave w owns row-eighth w; lane reads its own column
// (coalesced dwords), 16-row register double-buffer, zero ds_read in the scan.
// 78 KB LDS -> 2 blocks/CU = 16 waves/CU (64 KB loads in flight: HBM-BW-bound).
// Padding written for INPUT chunks only; recurrent consumers use cnt.
// Block (0,0) inits sim state (ws 0xAA-poisoned each call).
__global__ void __launch_bounds__(512) k_build(
    const float* __restrict__ w_ae, const float* __restrict__ w_ai,
    uint16_t* __restrict__ rows, float* __restrict__ vals,
    int* __restrict__ cnt, float* __restrict__ csum, int* __restrict__ ovfA,
    float* __restrict__ gv, unsigned long long* __restrict__ gring,
    int* __restrict__ gtot, unsigned int* __restrict__ ctr) {
  __shared__ uint16_t rs_s[NWV * CAPE * BC];           // 24 KB
  __shared__ float    vs_s[NWV * CAPE * BC];           // 48 KB
  __shared__ int      kqs[NWV][BC];
  __shared__ float    sqs[NWV][BC];
  __shared__ int      wovf[NWV];
  const int tid   = threadIdx.x;
  const int lane  = tid & 63;
  const int wv    = tid >> 6;          // eighth index 0..7
  const int chunk = blockIdx.y;
  const int col0  = blockIdx.x * BC;

  if (blockIdx.x == 0 && blockIdx.y == 0) {   // fused init
    for (int i = tid; i < 8192; i += 512) gv[i] = 0.f;
    if (tid < 512) gring[tid] = (tid < 512) ? 0ull : 0ull;
    if (tid < 8) gtot[tid] = 0;
    if (tid < 2) ctr[tid] = 0u;
  }

  int j0, len, cap, off;
  chunk_info(chunk, j0, len, cap, off);
  const float* W; int nc, cc0;
  if (col0 < NE_N) { W = w_ae; nc = NE_N; cc0 = col0; }
  else             { W = w_ai; nc = NI_N; cc0 = col0 - NE_N; }

  const int qlen = len >> 3;           // 64 (input) or 100 (recurrent)
  const int j0w  = j0 + wv * qlen;
  const float* Wc = W + (size_t)j0w * nc + cc0 + lane;   // this lane's column base

  float cur[16], nxt[16];
  #pragma unroll
  for (int r = 0; r < 16; ++r) cur[r] = Wc[(size_t)r * nc];   // qlen >= 64 > 16

  int k = 0; float s = 0.f; int ovfl = 0;
  for (int t0 = 0; t0 < qlen; t0 += 16) {
    const int nt = t0 + 16;
    if (nt < qlen) {                   // prefetch next batch (independent loads)
      #pragma unroll
      for (int r = 0; r < 16; ++r) {
        int rq = nt + r; rq = rq < qlen ? rq : qlen - 1;
        nxt[r] = Wc[(size_t)rq * nc];
      }
    }
    const int rlim = (qlen - t0) < 16 ? (qlen - t0) : 16;
    #pragma unroll
    for (int r = 0; r < 16; ++r) {
      if (r < rlim) {
        float w = cur[r];
        if (w != 0.f) {
          if (k < CAPE) {
            rs_s[(wv * CAPE + k) * BC + lane] = (uint16_t)(j0w + t0 + r);
            vs_s[(wv * CAPE + k) * BC + lane] = w;
            s += w; ++k;               // ascending-row order == reference scan
          } else ovfl = 1;             // dropped nonzero -> void strong proof
        }
      }
    }
    #pragma unroll
    for (int r = 0; r < 16; ++r) cur[r] = nxt[r];
  }
  kqs[wv][lane] = k;
  sqs[wv][lane] = s;
  int anyo = __any(ovfl);
  if (lane == 0) wovf[wv] = anyo;
  __syncthreads();

  // merge: per-col 8-way prefix (each thread re-derives from kqs; broadcast reads)
  const int col = lane;
  int c[NWV + 1]; c[0] = 0;
  #pragma unroll
  for (int q = 0; q < NWV; ++q) c[q + 1] = c[q] + kqs[q][col];
  const int ktot = c[NWV];
  if (tid < BC) {
    cnt[chunk * NCOL + col0 + col] = ktot < cap ? ktot : cap;
    float ss = sqs[0][col];
    #pragma unroll
    for (int q = 1; q < NWV; ++q) ss += sqs[q][col];
    csum[chunk * NCOL + col0 + col] = ss;
    unsigned long long capov = __ballot(ktot > cap);
    if (tid == 0) {
      int o = capov ? 1 : 0;
      #pragma unroll
      for (int q = 0; q < NWV; ++q) o |= wovf[q];
      ovfA[blockIdx.y * gridDim.x + blockIdx.x] = o;
    }
  }
  const int wlim = (chunk < 2) ? cap : (ktot < cap ? ktot : cap);   // pad input only
  const size_t gb = (size_t)off * NCOL + col0;
  for (int kk = wv; kk < wlim; kk += NWV) {
    uint16_t rr = (uint16_t)j0; float vv = 0.f;
    if (kk < ktot) {
      int q = 0;
      #pragma unroll
      for (int qq = 1; qq < NWV; ++qq) if (kk >= c[qq]) q = qq;
      int loc = kk - c[q];
      rr = rs_s[(q * CAPE + loc) * BC + col];   // addr%32 == col%32 -> conflict-free
      vv = vs_s[(q * CAPE + loc) * BC + col];
    }
    rows[gb + (size_t)kk * NCOL + col] = rr;    // 64 contiguous cols: full lines
    vals[gb + (size_t)kk * NCOL + col] = vv;
  }
}

// ---------------- fused proof: partial reductions + last-block strong verdict -----
__global__ void __launch_bounds__(256) k_proof(
    const float* __restrict__ csum, float* __restrict__ sE, float* __restrict__ sI,
    const float* __restrict__ vals, float* __restrict__ minpart, float* __restrict__ mwpart,
    const int* __restrict__ ovfA, unsigned int* __restrict__ ctr, int* __restrict__ strongp) {
  const int tid = threadIdx.x;
  const int b = blockIdx.x;     // 96 blocks
  __shared__ float w4[4];
  __shared__ int lastS;
  float m = 1e30f;
  if (b < 32) {                       // per-col saturated sums + min of fl(sE+sI)
    int col = b * 256 + tid;
    if (col < NCOL) {
      float se = 0.f;
      #pragma unroll
      for (int c = 2; c <= 9; ++c) se += csum[c * NCOL + col];
      float si = csum[10 * NCOL + col] + csum[11 * NCOL + col];
      sE[col] = se;
      sI[col] = si;
      m = se + si;   // fp-add monotone: (drive+se)+si >= fl(se+si) when drive>=0
    }
  } else {                            // min over input-chunk ELL vals (drive >= 0 cert)
    const int n = IN_ENT * NCOL;
    for (int i = (b - 32) * 256 + tid; i < n; i += 64 * 256)
      m = fminf(m, vals[i]);
  }
  #pragma unroll
  for (int o = 32; o; o >>= 1) m = fminf(m, __shfl_down(m, o));
  if ((tid & 63) == 0) w4[tid >> 6] = m;
  __syncthreads();
  if (tid == 0) {
    float r = fminf(fminf(w4[0], w4[1]), fminf(w4[2], w4[3]));
    if (b < 32) minpart[b] = r; else mwpart[b - 32] = r;
    __threadfence();
    unsigned p = __hip_atomic_fetch_add(&ctr[0], 1u, __ATOMIC_ACQ_REL, __HIP_MEMORY_SCOPE_AGENT);
    lastS = (p == 95) ? 1 : 0;
  }
  __syncthreads();
  if (!lastS) return;
  __threadfence();                    // acquire: all 96 partials now visible
  float mb = (tid < 32) ? __hip_atomic_load(&minpart[tid], __ATOMIC_RELAXED, __HIP_MEMORY_SCOPE_AGENT) : 1e30f;
  float mw = (tid < 64) ? __hip_atomic_load(&mwpart[tid],  __ATOMIC_RELAXED, __HIP_MEMORY_SCOPE_AGENT) : 1e30f;
  int ov = 0;
  for (int i = tid; i < NBLD; i += 256)
    ov |= __hip_atomic_load(&ovfA[i], __ATOMIC_RELAXED, __HIP_MEMORY_SCOPE_AGENT);
  #pragma unroll
  for (int o = 32; o; o >>= 1) {
    mb = fminf(mb, __shfl_down(mb, o));
    mw = fminf(mw, __shfl_down(mw, o));
    ov |= __shfl_down(ov, o);
  }
  __shared__ float fm[4], fw[4]; __shared__ int fo[4];
  if ((tid & 63) == 0) { fm[tid >> 6] = mb; fw[tid >> 6] = mw; fo[tid >> 6] = ov; }
  __syncthreads();
  if (tid == 0) {
    float MB = fminf(fminf(fm[0], fm[1]), fminf(fm[2], fm[3]));
    float MW = fminf(fminf(fw[0], fw[1]), fminf(fw[2], fw[3]));
    int   OV = fo[0] | fo[1] | fo[2] | fo[3];
    strongp[0] = (MB >= 1.0f && MW >= 0.0f && OV == 0) ? 1 : 0;
  }
}

// ---------------- input drive (spikes computed inline from rand_p) ----------------
// pass 0 (strong): y<4 -> t in [4y,4y+4); y>=4 exit.  (!strong): y -> [40y,40y+40).
// pass 1 (strong && !sab only): y==0 -> [16,40); y>0 -> [40y,40y+40).
__global__ void __launch_bounds__(256) k_drive(
    const uint16_t* __restrict__ rows, const float* __restrict__ vals,
    const float* __restrict__ rand_p, const float* __restrict__ inp,
    float* __restrict__ drive,
    const int* __restrict__ strongp, const int* __restrict__ sabp, int pass) {
  int t0, t1;
  if (pass == 0) {
    if (strongp[0]) {
      if (blockIdx.y >= 4) return;
      t0 = blockIdx.y * 4; t1 = t0 + 4;
    } else { t0 = blockIdx.y * 40; t1 = t0 + 40; }
  } else {
    if (!strongp[0] || sabp[0]) return;
    t0 = blockIdx.y * 40; t1 = t0 + 40;
    if (blockIdx.y == 0) t0 = TSPLIT;   // backfill what pass 0 skipped
  }
  __shared__ uint16_t rs[IN_ENT * 64];
  __shared__ float    vs[IN_ENT * 64];
  __shared__ float    inps[INP_N];
  __shared__ float    act0[INP_N];
  __shared__ float    psum[4][64];
  const int tid = threadIdx.x, lane = tid & 63, ph = tid >> 6;
  const int col0 = blockIdx.x * 64;
  for (int idx = tid; idx < IN_ENT * 64; idx += 256) {   // stage ELL once (coalesced)
    int k = idx >> 6, l = idx & 63;
    rs[idx] = rows[(size_t)k * NCOL + col0 + l];
    vs[idx] = vals[(size_t)k * NCOL + col0 + l];
  }
  for (int i = tid; i < INP_N; i += 256) inps[i] = inp[i] * 0.5f;  // rate_scale
  __syncthreads();
  for (int t = t0; t < t1; ++t) {
    #pragma unroll
    for (int i = tid; i < INP_N; i += 256)
      act0[i] = (rand_p[(size_t)t * INP_N + i] <= inps[i]) ? 1.f : 0.f;
    __syncthreads();
    float acc = 0.f;
    for (int k = ph; k < IN_ENT; k += 4)
      acc += vs[k * 64 + lane] * act0[rs[k * 64 + lane]];
    psum[ph][lane] = acc;
    __syncthreads();
    if (ph == 0)
      drive[(size_t)t * NCOL + col0 + lane] =
        ((psum[0][lane] + psum[1][lane]) + psum[2][lane]) + psum[3][lane];
    __syncthreads();
  }
}

// ---------------- one grid-wide transient step (t=0..9), 1024 thr / 16 phases -----
__global__ void __launch_bounds__(1024) k_step(
    const uint16_t* __restrict__ rows, const float* __restrict__ vals,
    const int* __restrict__ cnt, const float* __restrict__ sE,
    const float* __restrict__ sI, const float* __restrict__ drive,
    float* __restrict__ gv, unsigned long long* __restrict__ gring,
    int* __restrict__ gtot, const int* __restrict__ strongp, int t) {
  __shared__ unsigned long long m[128];
  __shared__ float psum[16][64];
  const int tid = threadIdx.x, lane = tid & 63, ph = tid >> 6;   // ph 0..15
  const int blk = blockIdx.x;
  const bool isE = (blk < 100);
  const int sw = t & 3, s1 = (t + 3) & 3, s2 = (t + 2) & 3;

  // ultra-fast: strong + 2 consecutive all-fire steps => provably all-fire again
  const bool full1 = (gtot[s1] == NE_N) && (gtot[4 + s1] == NI_N);
  const bool full2 = (gtot[s2] == NE_N) && (gtot[4 + s2] == NI_N);
  if (strongp[0] && full1 && full2) {
    if (tid == 0) {
      gring[sw * 128 + blk] = ~0ull;
      if (blk == 0) { gtot[sw] = NE_N; gtot[4 + sw] = NI_N; }
    }
    return;
  }

  const int sEs = isE ? s2 : s1;   // E targets: E rows t-2, I rows t-1; I reversed
  const int sIs = isE ? s1 : s2;
  const int col = blk * 64 + lane;

  if (tid < 100)      m[tid] = gring[sEs * 128 + tid];
  else if (tid < 125) m[tid] = gring[sIs * 128 + tid];
  const int pEv = gtot[sEs];
  const int pIv = gtot[4 + sIs];
  if (blk == 0 && tid == 0) { gtot[(t + 1) & 3] = 0; gtot[4 + ((t + 1) & 3)] = 0; }
  __syncthreads();

  float acc = 0.f;
  if (pEv > 0 && pEv < NE_N) {
    for (int c = 2; c <= 9; ++c) {
      int cn = cnt[c * NCOL + col];
      size_t base = (size_t)(112 + (c - 2) * 88) * NCOL + col;
      for (int k = ph; k < cn; k += 16) {
        int r = rows[base + (size_t)k * NCOL] - 1024;
        float wv = vals[base + (size_t)k * NCOL];
        if ((m[r >> 6] >> (r & 63)) & 1ull) acc += wv;
      }
    }
  }
  if (pIv > 0 && pIv < NI_N) {
    for (int c = 10; c <= 11; ++c) {
      int cn = cnt[c * NCOL + col];
      size_t base = (size_t)(112 + (c - 2) * 88) * NCOL + col;
      for (int k = ph; k < cn; k += 16) {
        int r = rows[base + (size_t)k * NCOL] - 1024;
        float wv = vals[base + (size_t)k * NCOL];
        if ((m[r >> 6] >> (r & 63)) & 1ull) acc += wv;
      }
    }
  }
  psum[ph][lane] = acc;
  __syncthreads();

  if (ph == 0) {
    float ps = 0.f;
    #pragma unroll
    for (int q = 0; q < 16; ++q) ps += psum[q][lane];
    float tot = drive[(size_t)t * NCOL + col] + ps;
    if (pEv == NE_N) tot += sE[col];
    if (pIv == NI_N) tot += sI[col];
    float vn = gv[col] * 0.95f + tot;
    int s = (vn >= 0.5f) ? 1 : 0;
    gv[col] = s ? 0.f : vn;
    unsigned long long bal = __ballot(s);
    int pc = __popcll(bal);
    if (lane == 0) {
      gring[sw * 128 + blk] = bal;
      if (isE) atomicAdd(&gtot[sw], pc);
      else     atomicAdd(&gtot[4 + sw], pc);
    }
  }
}

// ---------------- k_tail: steps t=10..15 in ONE launch -----------------------------
__global__ void __launch_bounds__(512) k_tail(
    const uint16_t* __restrict__ rows, const float* __restrict__ vals,
    const int* __restrict__ cnt, const float* __restrict__ sE,
    const float* __restrict__ sI, const float* __restrict__ drive,
    float* __restrict__ gv, unsigned long long* __restrict__ gring,
    int* __restrict__ gtot, const int* __restrict__ strongp,
    unsigned int* __restrict__ ctr) {
  __shared__ unsigned long long m[128];
  __shared__ float psum[8][64];
  const int tid = threadIdx.x, lane = tid & 63, ph = tid >> 6;
  const int blk = blockIdx.x;
  const bool isE = (blk < 100);

  const bool full8 = (gtot[0] == NE_N) && (gtot[4] == NI_N);   // t=8 -> slot 0
  const bool full9 = (gtot[1] == NE_N) && (gtot[5] == NI_N);   // t=9 -> slot 1
  if (strongp[0] && full8 && full9) {
    if (blk == 0) {
      for (int i = tid; i < 512; i += 512) gring[i] = ~0ull;
      if (tid < 4) { gtot[tid] = NE_N; gtot[4 + tid] = NI_N; }
    }
    return;
  }

  // ---- dormant: exact steps 10..15, device barrier between steps ----
  for (int t = 10; t < 16; ++t) {
    const int sw = t & 3, s1 = (t + 3) & 3, s2 = (t + 2) & 3;
    const int sEs = isE ? s2 : s1, sIs = isE ? s1 : s2;
    if (tid < 100)
      m[tid] = __hip_atomic_load(&gring[sEs * 128 + tid], __ATOMIC_RELAXED, __HIP_MEMORY_SCOPE_AGENT);
    else if (tid < 125)
      m[tid] = __hip_atomic_load(&gring[sIs * 128 + tid], __ATOMIC_RELAXED, __HIP_MEMORY_SCOPE_AGENT);
    const int pEv = __hip_atomic_load(&gtot[sEs], __ATOMIC_RELAXED, __HIP_MEMORY_SCOPE_AGENT);
    const int pIv = __hip_atomic_load(&gtot[4 + sIs], __ATOMIC_RELAXED, __HIP_MEMORY_SCOPE_AGENT);
    if (blk == 0 && tid == 0) {
      __hip_atomic_store(&gtot[(t + 1) & 3], 0, __ATOMIC_RELAXED, __HIP_MEMORY_SCOPE_AGENT);
      __hip_atomic_store(&gtot[4 + ((t + 1) & 3)], 0, __ATOMIC_RELAXED, __HIP_MEMORY_SCOPE_AGENT);
    }
    __syncthreads();

    const int col = blk * 64 + lane;
    float acc = 0.f;
    if (pEv > 0 && pEv < NE_N) {
      for (int c = 2; c <= 9; ++c) {
        int cn = cnt[c * NCOL + col];
        size_t base = (size_t)(112 + (c - 2) * 88) * NCOL + col;
        for (int k = ph; k < cn; k += 8) {
          int r = rows[base + (size_t)k * NCOL] - 1024;
          float wv = vals[base + (size_t)k * NCOL];
          if ((m[r >> 6] >> (r & 63)) & 1ull) acc += wv;
        }
      }
    }
    if (pIv > 0 && pIv < NI_N) {
      for (int c = 10; c <= 11; ++c) {
        int cn = cnt[c * NCOL + col];
        size_t base = (size_t)(112 + (c - 2) * 88) * NCOL + col;
        for (int k = ph; k < cn; k += 8) {
          int r = rows[base + (size_t)k * NCOL] - 1024;
          float wv = vals[base + (size_t)k * NCOL];
          if ((m[r >> 6] >> (r & 63)) & 1ull) acc += wv;
        }
      }
    }
    psum[ph][lane] = acc;
    __syncthreads();

    if (ph == 0) {
      float tot = drive[(size_t)t * NCOL + col]
                + ((psum[0][lane] + psum[1][lane]) + (psum[2][lane] + psum[3][lane]))
                + ((psum[4][lane] + psum[5][lane]) + (psum[6][lane] + psum[7][lane]));
      if (pEv == NE_N) tot += sE[col];
      if (pIv == NI_N) tot += sI[col];
      float vn = gv[col] * 0.95f + tot;
      int s = (vn >= 0.5f) ? 1 : 0;
      gv[col] = s ? 0.f : vn;
      unsigned long long bal = __ballot(s);
      int pc = __popcll(bal);
      if (lane == 0) {
        __hip_atomic_store(&gring[sw * 128 + blk], bal, __ATOMIC_RELAXED, __HIP_MEMORY_SCOPE_AGENT);
        if (isE) atomicAdd(&gtot[sw], pc);
        else     atomicAdd(&gtot[4 + sw], pc);
      }
    }
    __syncthreads();
    if (tid == 0) {       // device barrier (monotonic, agent scope)
      __threadfence();
      __hip_atomic_fetch_add(&ctr[1], 1u, __ATOMIC_RELEASE, __HIP_MEMORY_SCOPE_AGENT);
      const unsigned tgt = (unsigned)(t - 9) * 125;
      while (__hip_atomic_load(&ctr[1], __ATOMIC_ACQUIRE, __HIP_MEMORY_SCOPE_AGENT) < tgt)
        __builtin_amdgcn_s_sleep(1);
    }
    __syncthreads();
  }
}

// ---------------- sab: all-fire at t=13 (slot1), t=14 (slot2), t=15 (slot3) -------
__global__ void k_sab(const int* __restrict__ gtot, int* __restrict__ sab) {
  sab[0] = (gtot[1] == NE_N && gtot[2] == NE_N && gtot[3] == NE_N &&
            gtot[5] == NI_N && gtot[6] == NI_N && gtot[7] == NI_N) ? 1 : 0;
}

// ---------------- flag[t] (125 strided blocks; pure early-exit when proven) -------
__global__ void __launch_bounds__(256) k_check2(
    const float* __restrict__ drive, const float* __restrict__ sE,
    const float* __restrict__ sI, int* __restrict__ flag,
    const int* __restrict__ strongp, const int* __restrict__ sabp) {
  if (strongp[0] && sabp[0]) return;
  const int tid = threadIdx.x;
  __shared__ int w4[4];
  for (int t = blockIdx.x; t < TS_N; t += 125) {
    const float* dr = drive + (size_t)t * NCOL;
    int nb = 0;
    for (int col = tid; col < NCOL; col += 256) {
      float vn = (dr[col] + sE[col]) + sI[col];
      nb += (vn >= 0.5f) ? 0 : 1;
    }
    #pragma unroll
    for (int o = 32; o; o >>= 1) nb += __shfl_down(nb, o);
    if ((tid & 63) == 0) w4[tid >> 6] = nb;
    __syncthreads();
    if (tid == 0) flag[t] = ((w4[0] + w4[1]) + (w4[2] + w4[3])) == 0 ? 1 : 0;
    __syncthreads();
  }
}

// ---------------- allflag: strong proof OR AND of flag[t>=TSPLIT] ----------------
__global__ void k_fin(const int* __restrict__ flag, const int* __restrict__ strongp,
                      int* __restrict__ allflag) {
  const int tid = threadIdx.x;   // 256
  if (strongp[0]) { if (tid == 0) allflag[0] = 1; return; }
  int bad = 0;
  for (int i = TSPLIT + tid; i < TS_N; i += 256) bad += (flag[i] == 0) ? 1 : 0;
  #pragma unroll
  for (int o = 32; o; o >>= 1) bad += __shfl_down(bad, o);
  __shared__ int w4[4];
  if ((tid & 63) == 0) w4[tid >> 6] = bad;
  __syncthreads();
  if (tid == 0) allflag[0] = ((w4[0] + w4[1]) + (w4[2] + w4[3])) == 0 ? 1 : 0;
}

// ---------------- k_simB: t in [TSPLIT, TS); short-circuits if saturation proven ----
__global__ void __launch_bounds__(1024) k_simB(
    const uint16_t* __restrict__ rows, const float* __restrict__ vals,
    const int* __restrict__ cnt, const float* __restrict__ sE,
    const float* __restrict__ sI, const float* __restrict__ drive,
    const int* __restrict__ flag,
    const float* __restrict__ stv, const unsigned long long* __restrict__ str_,
    const int* __restrict__ stt, const int* __restrict__ sab,
    const int* __restrict__ allflag, float* __restrict__ out) {
  __shared__ unsigned long long ring[4][128];
  __shared__ int pEtot[4], pItot[4];
  __shared__ int flagsL[TS_N];
  __shared__ int fastexit;

  const int tid  = threadIdx.x;
  const int lane = tid & 63;
  const int wv   = tid >> 6;

  if (tid == 0) fastexit = (sab[0] != 0) && (allflag[0] != 0);
  __syncthreads();

  if (fastexit) {
    // all-fire at 13,14,15 + (strong proof or per-t flags) for t>=16 => v stays 0,
    // every col fires every step t>=16; probe [200,1000) => 800/800 = 1.0 exactly.
    #pragma unroll
    for (int p = 0; p < 8; ++p) {
      int col = p * 1024 + tid;
      if (col < NE_N) out[col] = 1.0f;
    }
    return;
  }

  // ---- verified fallback: 1-CU sequential loop from saved transient state ----
  for (int i = tid; i < 512; i += 1024) (&ring[0][0])[i] = str_[i];
  if (tid < 4) { pEtot[tid] = stt[tid]; pItot[tid] = stt[4 + tid]; }
  for (int i = tid; i < TS_N; i += 1024) flagsL[i] = flag[i];

  float v[8], sEr[8], sIr[8];
  int spk[8];
  #pragma unroll
  for (int p = 0; p < 8; ++p) {
    int col = p * 1024 + tid;
    sEr[p] = (col < NCOL) ? sE[col] : 0.f;
    sIr[p] = (col < NCOL) ? sI[col] : 0.f;
    v[p] = (col < NCOL) ? stv[col] : 0.f; spk[p] = 0;
  }
  int spkAll = 0, fastAge = 0;
  __syncthreads();

  for (int t = TSPLIT; t < TS_N; ++t) {
    const int sw = t & 3, s1 = (t + 3) & 3, s2 = (t + 2) & 3;
    int pE1, pI1, pE2, pI2;
    if (fastAge >= 2)      { pE1 = pE2 = NE_N; pI1 = pI2 = NI_N; }
    else if (fastAge == 1) { pE1 = NE_N; pI1 = NI_N; pE2 = pEtot[s2]; pI2 = pItot[s2]; }
    else                   { pE1 = pEtot[s1]; pI1 = pItot[s1]; pE2 = pEtot[s2]; pI2 = pItot[s2]; }
    const bool satE1 = (pE1 == NE_N), satE2 = (pE2 == NE_N);
    const bool satI1 = (pI1 == NI_N), satI2 = (pI2 == NI_N);

    if (satE1 && satI1 && satE2 && satI2 && flagsL[t]) {
      if (t >= PRB0_T) ++spkAll;
      ++fastAge;
      continue;
    }

    if (fastAge > 0) {
      for (int i = tid; i < 128; i += 1024) {
        ring[s1][i] = ~0ull;
        if (fastAge >= 2) ring[s2][i] = ~0ull;
      }
    }
    if (tid == 0) {
      if (fastAge > 0) {
        pEtot[s1] = NE_N; pItot[s1] = NI_N;
        if (fastAge >= 2) { pEtot[s2] = NE_N; pItot[s2] = NI_N; }
      }
      pEtot[sw] = 0; pItot[sw] = 0;
    }
    __syncthreads();
    fastAge = 0;

    const float* dr = drive + (size_t)t * NCOL;
    int myE = 0, myI = 0;
    #pragma unroll
    for (int p = 0; p < 8; ++p) {
      int col = p * 1024 + tid;
      bool isEcol = col < NE_N;
      int pEv = isEcol ? pE2 : pE1;
      int pIv = isEcol ? pI1 : pI2;
      int sEs = isEcol ? s2 : s1;
      int sIs = isEcol ? s1 : s2;
      float tot = (col < NCOL) ? dr[col] : 0.f;
      if (col < NCOL) {
        if (pEv == NE_N) tot += sEr[p];
        else if (pEv > 0) {
          for (int c = 2; c <= 9; ++c) {
            int cn = cnt[c * NCOL + col];
            size_t base = (size_t)(112 + (c - 2) * 88) * NCOL + col;
            for (int k = 0; k < cn; ++k) {
              int j = rows[base + (size_t)k * NCOL];
              float wval = vals[base + (size_t)k * NCOL];
              int r = j - 1024;
              if ((ring[sEs][r >> 6] >> (r & 63)) & 1ull) tot += wval;
            }
          }
        }
        if (pIv == NI_N) tot += sIr[p];
        else if (pIv > 0) {
          for (int c = 10; c <= 11; ++c) {
            int cn = cnt[c * NCOL + col];
            size_t base = (size_t)(112 + (c - 2) * 88) * NCOL + col;
            for (int k = 0; k < cn; ++k) {
              int j = rows[base + (size_t)k * NCOL];
              float wval = vals[base + (size_t)k * NCOL];
              int r = j - 1024;
              if ((ring[sIs][r >> 6] >> (r & 63)) & 1ull) tot += wval;
            }
          }
        }
      }
      float vn = v[p] * 0.95f + tot;
      int s = (col < NCOL) && (vn >= 0.5f);
      v[p] = s ? 0.f : vn;
      if (t >= PRB0_T && isEcol) spk[p] += s;
      unsigned long long bal = __ballot(s);
      int word = p * 16 + wv;
      if (word < 125) {
        int pc = __popcll(bal);
        if (word < 100) myE += pc; else myI += pc;
        if (lane == 0) ring[sw][word] = bal;
      }
    }
    if (lane == 0) { atomicAdd(&pEtot[sw], myE); atomicAdd(&pItot[sw], myI); }
    __syncthreads();
  }

  #pragma unroll
  for (int p = 0; p < 8; ++p) {
    int col = p * 1024 + tid;
    if (col < NE_N) out[col] = (float)(spk[p] + spkAll) / 800.0f;
  }
}

// ---------------- launch (18 dispatches) ----------------
extern "C" void kernel_launch(void* const* d_in, const int* in_sizes, int n_in,
                              void* d_out, int out_size, void* d_ws, size_t ws_size,
                              hipStream_t stream) {
  const float* inp    = (const float*)d_in[0];
  const float* w_ae   = (const float*)d_in[1];
  const float* w_ai   = (const float*)d_in[2];
  const float* rand_p = (const float*)d_in[3];

  char* ws = (char*)d_ws;
  uint16_t*           rows    = (uint16_t*)(ws + ROWS_OFF);
  float*              vals    = (float*)(ws + VALS_OFF);
  int*                cnt     = (int*)(ws + CNT_OFF);
  float*              csum    = (float*)(ws + CSUM_OFF);
  float*              drive   = (float*)(ws + DRV_OFF);
  float*              sEa     = (float*)(ws + SE_OFF);
  float*              sIa     = (float*)(ws + SI_OFF);
  int*                flag    = (int*)(ws + FLG_OFF);
  float*              gv      = (float*)(ws + STV_OFF);
  unsigned long long* gring   = (unsigned long long*)(ws + STR_OFF);
  int*                gtot    = (int*)(ws + STT_OFF);
  int*                sab     = (int*)(ws + SAB_OFF);
  int*                afl     = (int*)(ws + AFL_OFF);
  float*              minpart = (float*)(ws + MNP_OFF);
  float*              mwpart  = (float*)(ws + MNW_OFF);
  int*                strg    = (int*)(ws + STG_OFF);
  int*                ovfA    = (int*)(ws + OVA_OFF);
  unsigned int*       ctr     = (unsigned int*)(ws + CTR_OFF);

  k_build<<<dim3(NCOL / BC, NCHUNK), 512, 0, stream>>>(w_ae, w_ai, rows, vals, cnt, csum,
                                                       ovfA, gv, gring, gtot, ctr);
  k_proof<<<96, 256, 0, stream>>>(csum, sEa, sIa, vals, minpart, mwpart, ovfA, ctr, strg);
  k_drive<<<dim3(125, 25), 256, 0, stream>>>(rows, vals, rand_p, inp, drive, strg, sab, 0);
  for (int t = 0; t < 10; ++t)
    k_step<<<125, 1024, 0, stream>>>(rows, vals, cnt, sEa, sIa, drive, gv, gring, gtot, strg, t);
  k_tail<<<125, 512, 0, stream>>>(rows, vals, cnt, sEa, sIa, drive, gv, gring, gtot, strg, ctr);
  k_sab<<<1, 1, 0, stream>>>(gtot, sab);
  // lazy fallback fill: only active if strong proof held but transient did not saturate
  k_drive<<<dim3(125, 25), 256, 0, stream>>>(rows, vals, rand_p, inp, drive, strg, sab, 1);
  k_check2<<<125, 256, 0, stream>>>(drive, sEa, sIa, flag, strg, sab);
  k_fin<<<1, 256, 0, stream>>>(flag, strg, afl);
  k_simB<<<1, 1024, 0, stream>>>(rows, vals, cnt, sEa, sIa, drive, flag,
                                 gv, gring, gtot, sab, afl, (float*)d_out);
}